// Round 6
// baseline (382.136 us; speedup 1.0000x reference)
//
#include <hip/hip_runtime.h>
#include <hip/hip_bf16.h>

#define B_ 4
#define S_ 2048
#define D_ 1024
#define H_ 16
#define HD_ 64
#define M_ (B_*S_)
#define BH_ (B_*H_)

typedef __bf16 bf16;
typedef __attribute__((ext_vector_type(8))) __bf16 bf16x8;
typedef __attribute__((ext_vector_type(4))) __bf16 bf16x4;
typedef __attribute__((ext_vector_type(4))) float f32x4;
typedef __attribute__((ext_vector_type(16))) float f32x16;
typedef __attribute__((ext_vector_type(4))) unsigned u32x4;

#define MFMA16(a,b,c) __builtin_amdgcn_mfma_f32_16x16x32_bf16((a),(b),(c),0,0,0)
#define MFMA32(a,b,c) __builtin_amdgcn_mfma_f32_32x32x16_bf16((a),(b),(c),0,0,0)

__device__ __forceinline__ void gl2lds16(const void* g, void* l) {
  __builtin_amdgcn_global_load_lds(
      (__attribute__((address_space(1))) void*)(g),
      (__attribute__((address_space(3))) void*)(l), 16, 0, 0);
}

__device__ __forceinline__ float fexp2(float x) {
  float r;
  asm("v_exp_f32 %0, %1" : "=v"(r) : "v"(x));
  return r;
}

__device__ __forceinline__ unsigned cvtpk(float lo, float hi) {
  unsigned r;
  asm("v_cvt_pk_bf16_f32 %0, %1, %2" : "=v"(r) : "v"(lo), "v"(hi));
  return r;
}

// ---------------- f32 -> bf16 convert ----------------
__global__ __launch_bounds__(256) void k_cvt(const float* __restrict__ in,
                                             bf16* __restrict__ out, int n) {
  int i = (blockIdx.x * 256 + threadIdx.x) * 4;
  if (i >= n) return;
  f32x4 v = *(const f32x4*)(in + i);
  bf16x4 o;
  o[0] = (bf16)v[0]; o[1] = (bf16)v[1]; o[2] = (bf16)v[2]; o[3] = (bf16)v[3];
  *(bf16x4*)(out + i) = o;
}

// ============ fused QKV GEMM: C[m,n] = X[m,:]·Wcat[n,:] + bias, n in [0,3072) ====
// 128x128 tile, BK=64, 8 waves (2x4), frag-linear LDS (all ds_read_b128 are
// base + lane*16 + imm), XCD-swizzled 1D grid (1536 blocks, 192/XCD = 8 M-rows).
__global__ __launch_bounds__(512, 4) void k_gemm_qkv(
    const bf16* __restrict__ A, const bf16* __restrict__ Wc,
    const float* __restrict__ bq, const float* __restrict__ bk,
    const float* __restrict__ bvp,
    bf16* __restrict__ Qb, bf16* __restrict__ Kb, bf16* __restrict__ Vt,
    float scl_q) {
  __shared__ __align__(16) bf16 As[2][16 * 512];
  __shared__ __align__(16) bf16 Bs[2][16 * 512];
  const int t = threadIdx.x;
  const int l = t & 63, w = t >> 6;
  const int g = l >> 4, c = l & 15;
  const int wm = w >> 2, wn = w & 3;

  const int bid = blockIdx.x;
  const int lg = (bid & 7) * 192 + (bid >> 3);   // bijective XCD swizzle
  const int xt = lg % 24, yt = lg / 24;
  const int m0 = yt * 128, n0 = xt * 128;
  const int sec = n0 >> 10;                       // 0=Q, 1=K, 2=V

  f32x4 acc[4][2];
#pragma unroll
  for (int i = 0; i < 4; ++i)
#pragma unroll
    for (int j = 0; j < 2; ++j) acc[i][j] = (f32x4)(0.0f);

  // staging: frag f = p*8 + w holds rows (f>>1)*16+(l&15), k-chunk (f&1)*4+(l>>4)
#define STG(buf, k0)                                                          \
  do {                                                                        \
    for (int p = 0; p < 2; ++p) {                                             \
      const int f = p * 8 + w;                                                \
      const int row = (f >> 1) * 16 + (l & 15);                               \
      const int kc = (f & 1) * 4 + (l >> 4);                                  \
      gl2lds16(A + (size_t)(m0 + row) * D_ + (k0) + kc * 8,                   \
               &As[buf][f * 512]);                                            \
      gl2lds16(Wc + (size_t)(n0 + row) * D_ + (k0) + kc * 8,                  \
               &Bs[buf][f * 512]);                                            \
    }                                                                         \
  } while (0)

  STG(0, 0);
  __syncthreads();

  for (int kt = 0; kt < D_ / 64; ++kt) {
    const int cur = kt & 1;
    if (kt + 1 < D_ / 64) STG(cur ^ 1, (kt + 1) * 64);
#pragma unroll
    for (int kk = 0; kk < 2; ++kk) {
      bf16x8 af[4], bw[2];
#pragma unroll
      for (int i = 0; i < 4; ++i)
        af[i] = *(const bf16x8*)&As[cur][(((wm * 4 + i) * 2 + kk) * 512) + l * 8];
#pragma unroll
      for (int j = 0; j < 2; ++j)
        bw[j] = *(const bf16x8*)&Bs[cur][(((wn * 2 + j) * 2 + kk) * 512) + l * 8];
#pragma unroll
      for (int i = 0; i < 4; ++i)
#pragma unroll
        for (int j = 0; j < 2; ++j) acc[i][j] = MFMA16(af[i], bw[j], acc[i][j]);
    }
    __syncthreads();
  }
#undef STG

  const float* bptr = (sec == 0) ? bq : (sec == 1) ? bk : bvp;
  const float scl = (sec == 0) ? scl_q : 1.0f;
  bf16* outp = (sec == 0) ? Qb : (sec == 1) ? Kb : Vt;
  const int nbase = (n0 & 1023) + wn * 32;

  float bvj[2];
#pragma unroll
  for (int j = 0; j < 2; ++j) bvj[j] = bptr[nbase + j * 16 + c];

#pragma unroll
  for (int i = 0; i < 4; ++i) {
#pragma unroll
    for (int j = 0; j < 2; ++j) {
#pragma unroll
      for (int r = 0; r < 4; ++r) {
        const int m = m0 + wm * 64 + i * 16 + g * 4 + r;
        const int nloc = nbase + j * 16 + c;
        const float v = (acc[i][j][r] + bvj[j]) * scl;
        const int b = m >> 11, s = m & (S_ - 1);
        const int h = nloc >> 6, hd = nloc & 63;
        size_t idx;
        if (sec < 2) idx = (((size_t)(b * H_ + h)) * S_ + s) * HD_ + hd;
        else         idx = (((size_t)(b * H_ + h)) * HD_ + hd) * S_ + s;
        outp[idx] = (bf16)v;
      }
    }
  }
}

// ============ O-projection GEMM + residual: Y = Ob·Wo^T + bo + X (f32) ========
__global__ __launch_bounds__(512, 4) void k_gemm_o(
    const bf16* __restrict__ A, const bf16* __restrict__ Wc,
    const float* __restrict__ bias, const float* __restrict__ Xres,
    float* __restrict__ Yb) {
  __shared__ __align__(16) bf16 As[2][16 * 512];
  __shared__ __align__(16) bf16 Bs[2][16 * 512];
  const int t = threadIdx.x;
  const int l = t & 63, w = t >> 6;
  const int g = l >> 4, c = l & 15;
  const int wm = w >> 2, wn = w & 3;

  const int bid = blockIdx.x;
  const int lg = (bid & 7) * 64 + (bid >> 3);
  const int xt = lg & 7, yt = lg >> 3;
  const int m0 = yt * 128, n0 = xt * 128;

  f32x4 acc[4][2];
#pragma unroll
  for (int i = 0; i < 4; ++i)
#pragma unroll
    for (int j = 0; j < 2; ++j) acc[i][j] = (f32x4)(0.0f);

#define STG(buf, k0)                                                          \
  do {                                                                        \
    for (int p = 0; p < 2; ++p) {                                             \
      const int f = p * 8 + w;                                                \
      const int row = (f >> 1) * 16 + (l & 15);                               \
      const int kc = (f & 1) * 4 + (l >> 4);                                  \
      gl2lds16(A + (size_t)(m0 + row) * D_ + (k0) + kc * 8,                   \
               &As[buf][f * 512]);                                            \
      gl2lds16(Wc + (size_t)(n0 + row) * D_ + (k0) + kc * 8,                  \
               &Bs[buf][f * 512]);                                            \
    }                                                                         \
  } while (0)

  STG(0, 0);
  __syncthreads();

  for (int kt = 0; kt < D_ / 64; ++kt) {
    const int cur = kt & 1;
    if (kt + 1 < D_ / 64) STG(cur ^ 1, (kt + 1) * 64);
#pragma unroll
    for (int kk = 0; kk < 2; ++kk) {
      bf16x8 af[4], bw[2];
#pragma unroll
      for (int i = 0; i < 4; ++i)
        af[i] = *(const bf16x8*)&As[cur][(((wm * 4 + i) * 2 + kk) * 512) + l * 8];
#pragma unroll
      for (int j = 0; j < 2; ++j)
        bw[j] = *(const bf16x8*)&Bs[cur][(((wn * 2 + j) * 2 + kk) * 512) + l * 8];
#pragma unroll
      for (int i = 0; i < 4; ++i)
#pragma unroll
        for (int j = 0; j < 2; ++j) acc[i][j] = MFMA16(af[i], bw[j], acc[i][j]);
    }
    __syncthreads();
  }
#undef STG

  float bvj[2];
#pragma unroll
  for (int j = 0; j < 2; ++j) bvj[j] = bias[n0 + wn * 32 + j * 16 + c];

#pragma unroll
  for (int i = 0; i < 4; ++i) {
#pragma unroll
    for (int j = 0; j < 2; ++j) {
#pragma unroll
      for (int r = 0; r < 4; ++r) {
        const int m = m0 + wm * 64 + i * 16 + g * 4 + r;
        const int n = n0 + wn * 32 + j * 16 + c;
        Yb[(size_t)m * D_ + n] =
            acc[i][j][r] + bvj[j] + Xres[(size_t)m * D_ + n];
      }
    }
  }
}

// ---------------- flash attention, 32x32 fully-swapped, frag-linear LDS ------
// 1D grid 1024 (XCD-swizzled: 8 heads/XCD -> K/V L2-resident), 4 waves,
// each wave 32 q rows. K/V tiles 64x64 staged in MFMA-fragment order:
// frag f (=kk*2+half) at Ks[f*512 + lane*8] -> every ds_read_b128 is linear.
__global__ __launch_bounds__(256, 4) void k_attn(const bf16* __restrict__ Q,
                                                 const bf16* __restrict__ K,
                                                 const bf16* __restrict__ Vt,
                                                 bf16* __restrict__ O) {
  __shared__ __align__(16) bf16 Ks[2][8 * 512];
  __shared__ __align__(16) bf16 Vs[2][8 * 512];
  const int t = threadIdx.x;
  const int l = t & 63, w = t >> 6;
  const int c32 = l & 31, hi = l >> 5;

  const int bid = blockIdx.x;
  const int lg = (bid & 7) * 128 + (bid >> 3);
  const int bh = lg >> 4;
  const int q0 = (lg & 15) * 128 + w * 32;

  const bf16* Qh = Q + (size_t)bh * S_ * HD_;
  const bf16* Kh = K + (size_t)bh * S_ * HD_;
  const bf16* Vh = Vt + (size_t)bh * HD_ * S_;

  // Q B-fragments, persistent in registers (pre-scaled by 1/sqrt(HD)*log2e)
  bf16x8 qf[4];
#pragma unroll
  for (int kk = 0; kk < 4; ++kk)
    qf[kk] = *(const bf16x8*)&Qh[(size_t)(q0 + c32) * HD_ + kk * 16 + hi * 8];

  f32x16 acc0 = (f32x16)(0.f), acc1 = (f32x16)(0.f);
  float m_c = -__builtin_inff(), l_c = 0.f;

  // staging: frag f = p*4 + w; half = f&1 (rows 0-31 / 32-63); kk2 = f>>1.
  // K frag lane l: row = half*32+(l&31), k-chunk kk2*2+(l>>5).
  // V frag lane l: d-row = half*32+(l&31), s-chunk kk2*2+(l>>5).
#define STGA(buf, kt)                                                         \
  do {                                                                        \
    for (int p = 0; p < 2; ++p) {                                             \
      const int f = p * 4 + w;                                                \
      const int row = (f & 1) * 32 + (l & 31);                                \
      const int c8 = (f >> 1) * 2 + (l >> 5);                                 \
      gl2lds16(Kh + (size_t)((kt) * 64 + row) * HD_ + c8 * 8,                 \
               &Ks[buf][f * 512]);                                            \
      gl2lds16(Vh + (size_t)row * S_ + (kt) * 64 + c8 * 8,                    \
               &Vs[buf][f * 512]);                                            \
    }                                                                         \
  } while (0)

  STGA(0, 0);
  __syncthreads();

  for (int kt = 0; kt < S_ / 64; ++kt) {
    const int cur = kt & 1;
    if (kt + 1 < S_ / 64) STGA(cur ^ 1, kt + 1);

    // ---- QK^T (swapped): st = K * Q^T ----
    f32x16 st0 = (f32x16)(0.f), st1 = (f32x16)(0.f);
    __builtin_amdgcn_s_setprio(1);
#pragma unroll
    for (int kk = 0; kk < 4; ++kk) {
      bf16x8 kf0 = *(const bf16x8*)&Ks[cur][(kk * 2) * 512 + l * 8];
      bf16x8 kf1 = *(const bf16x8*)&Ks[cur][(kk * 2 + 1) * 512 + l * 8];
      st0 = MFMA32(kf0, qf[kk], st0);
      st1 = MFMA32(kf1, qf[kk], st1);
    }
    __builtin_amdgcn_s_setprio(0);

    // ---- online softmax, one scalar state per lane (q = c32) ----
    float tm;
    {
      f32x16 mx;
#pragma unroll
      for (int r = 0; r < 16; ++r) mx[r] = fmaxf(st0[r], st1[r]);
      float m8[8];
#pragma unroll
      for (int r = 0; r < 8; ++r) m8[r] = fmaxf(mx[r], mx[r + 8]);
      float m4[4];
#pragma unroll
      for (int r = 0; r < 4; ++r) m4[r] = fmaxf(m8[r], m8[r + 4]);
      tm = fmaxf(fmaxf(m4[0], m4[1]), fmaxf(m4[2], m4[3]));
      tm = fmaxf(tm, __shfl_xor(tm, 32));
    }
    if (!__all(tm <= m_c + 8.f)) {   // defer-max (T13)
      const float mn = fmaxf(m_c, tm);
      const float cf = fexp2(m_c - mn);
      m_c = mn;
      l_c *= cf;
#pragma unroll
      for (int r = 0; r < 16; ++r) { acc0[r] *= cf; acc1[r] *= cf; }
    }
    float rs = 0.f;
#pragma unroll
    for (int r = 0; r < 16; ++r) { st0[r] = fexp2(st0[r] - m_c); rs += st0[r]; }
#pragma unroll
    for (int r = 0; r < 16; ++r) { st1[r] = fexp2(st1[r] - m_c); rs += st1[r]; }
    rs += __shfl_xor(rs, 32);
    l_c += rs;

    // ---- P^T -> bf16 B-fragments in-register (cvt_pk + permlane32_swap) ----
    unsigned ca[8], cb[8];
#pragma unroll
    for (int i = 0; i < 8; ++i) {
      ca[i] = cvtpk(st0[2 * i], st0[2 * i + 1]);
      cb[i] = cvtpk(st1[2 * i], st1[2 * i + 1]);
    }
    asm volatile("v_permlane32_swap_b32 %0, %1" : "+v"(ca[0]), "+v"(ca[2]));
    asm volatile("v_permlane32_swap_b32 %0, %1" : "+v"(ca[1]), "+v"(ca[3]));
    asm volatile("v_permlane32_swap_b32 %0, %1" : "+v"(ca[4]), "+v"(ca[6]));
    asm volatile("v_permlane32_swap_b32 %0, %1" : "+v"(ca[5]), "+v"(ca[7]));
    asm volatile("v_permlane32_swap_b32 %0, %1" : "+v"(cb[0]), "+v"(cb[2]));
    asm volatile("v_permlane32_swap_b32 %0, %1" : "+v"(cb[1]), "+v"(cb[3]));
    asm volatile("v_permlane32_swap_b32 %0, %1" : "+v"(cb[4]), "+v"(cb[6]));
    asm volatile("v_permlane32_swap_b32 %0, %1" : "+v"(cb[5]), "+v"(cb[7]));
    bf16x8 pf[4];
    pf[0] = __builtin_bit_cast(bf16x8, (u32x4){ca[0], ca[1], ca[2], ca[3]});
    pf[1] = __builtin_bit_cast(bf16x8, (u32x4){ca[4], ca[5], ca[6], ca[7]});
    pf[2] = __builtin_bit_cast(bf16x8, (u32x4){cb[0], cb[1], cb[2], cb[3]});
    pf[3] = __builtin_bit_cast(bf16x8, (u32x4){cb[4], cb[5], cb[6], cb[7]});

    // ---- PV (swapped): acc(O^T) += V^T * P^T ----
    __builtin_amdgcn_s_setprio(1);
#pragma unroll
    for (int kb = 0; kb < 4; ++kb) {
      bf16x8 vf0 = *(const bf16x8*)&Vs[cur][(kb * 2) * 512 + l * 8];
      bf16x8 vf1 = *(const bf16x8*)&Vs[cur][(kb * 2 + 1) * 512 + l * 8];
      acc0 = MFMA32(vf0, pf[kb], acc0);
      acc1 = MFMA32(vf1, pf[kb], acc1);
    }
    __builtin_amdgcn_s_setprio(0);

    __syncthreads();
  }
#undef STGA

  const float li = 1.f / l_c;
  const int b = bh >> 4, h = bh & 15;
  const int q = q0 + c32;
  bf16* Orow = O + ((size_t)(b * S_ + q)) * D_ + h * 64;
#pragma unroll
  for (int rq = 0; rq < 4; ++rq) {
    bf16x4 o0, o1;
#pragma unroll
    for (int j = 0; j < 4; ++j) {
      o0[j] = (bf16)(acc0[rq * 4 + j] * li);
      o1[j] = (bf16)(acc1[rq * 4 + j] * li);
    }
    *(bf16x4*)&Orow[rq * 8 + hi * 4] = o0;
    *(bf16x4*)&Orow[32 + rq * 8 + hi * 4] = o1;
  }
}

// ---------------- LayerNorm (one block per row) ----------------
__global__ __launch_bounds__(256) void k_ln(const float* __restrict__ Y,
                                            const float* __restrict__ gamma,
                                            const float* __restrict__ beta,
                                            float* __restrict__ out) {
  __shared__ float red[8];
  const int row = blockIdx.x, t = threadIdx.x;
  const float* y = Y + (size_t)row * D_;
  f32x4 v = *(const f32x4*)(y + t * 4);
  float s = v[0] + v[1] + v[2] + v[3];
  float s2 = v[0]*v[0] + v[1]*v[1] + v[2]*v[2] + v[3]*v[3];
#pragma unroll
  for (int mk = 1; mk <= 32; mk <<= 1) {
    s += __shfl_xor(s, mk);
    s2 += __shfl_xor(s2, mk);
  }
  if ((t & 63) == 0) { red[t >> 6] = s; red[4 + (t >> 6)] = s2; }
  __syncthreads();
  const float ts = red[0] + red[1] + red[2] + red[3];
  const float ts2 = red[4] + red[5] + red[6] + red[7];
  const float mu = ts * (1.0f / D_);
  const float inv = rsqrtf(ts2 * (1.0f / D_) - mu * mu + 1e-12f);
  f32x4 gm = *(const f32x4*)(gamma + t * 4);
  f32x4 bt = *(const f32x4*)(beta + t * 4);
  f32x4 o;
#pragma unroll
  for (int j = 0; j < 4; ++j) o[j] = gm[j] * (v[j] - mu) * inv + bt[j];
  *(f32x4*)(out + (size_t)row * D_ + t * 4) = o;
}

extern "C" void kernel_launch(void* const* d_in, const int* in_sizes, int n_in,
                              void* d_out, int out_size, void* d_ws, size_t ws_size,
                              hipStream_t stream) {
  const float* X     = (const float*)d_in[0];
  const float* Wq    = (const float*)d_in[1];
  const float* bq    = (const float*)d_in[2];
  const float* Wk    = (const float*)d_in[3];
  const float* bk    = (const float*)d_in[4];
  const float* Wv    = (const float*)d_in[5];
  const float* bv    = (const float*)d_in[6];
  const float* Wo    = (const float*)d_in[7];
  const float* bo    = (const float*)d_in[8];
  const float* gamma = (const float*)d_in[9];
  const float* beta  = (const float*)d_in[10];

  char* ws = (char*)d_ws;
  bf16* Xb  = (bf16*)(ws + 0);                 // 16 MB
  bf16* Wcat= (bf16*)(ws + (16u << 20));       // 6 MB: Wq|Wk|Wv rows 0..3071
  bf16* Wob = (bf16*)(ws + (22u << 20));       // 2 MB
  bf16* Qb  = (bf16*)(ws + (24u << 20));       // 16 MB [bh][s][d] (pre-scaled)
  bf16* Kb  = (bf16*)(ws + (40u << 20));       // 16 MB [bh][s][d]
  bf16* Vt  = (bf16*)(ws + (56u << 20));       // 16 MB [bh][d][s]
  bf16* Ob  = (bf16*)(ws + (72u << 20));       // 16 MB [b,s,D]
  float* Yb = (float*)(ws + (88u << 20));      // 32 MB

  const float SCL = 0.125f * 1.44269504088896340736f;  // 1/sqrt(64) * log2(e)

  k_cvt<<<M_ * D_ / 1024, 256, 0, stream>>>(X, Xb, M_ * D_);
  k_cvt<<<D_ * D_ / 1024, 256, 0, stream>>>(Wq, Wcat, D_ * D_);
  k_cvt<<<D_ * D_ / 1024, 256, 0, stream>>>(Wk, Wcat + (size_t)D_ * D_, D_ * D_);
  k_cvt<<<D_ * D_ / 1024, 256, 0, stream>>>(Wv, Wcat + 2 * (size_t)D_ * D_, D_ * D_);
  k_cvt<<<D_ * D_ / 1024, 256, 0, stream>>>(Wo, Wob, D_ * D_);

  k_gemm_qkv<<<1536, 512, 0, stream>>>(Xb, Wcat, bq, bk, bv, Qb, Kb, Vt, SCL);
  k_attn<<<1024, 256, 0, stream>>>(Qb, Kb, Vt, Ob);
  k_gemm_o<<<512, 512, 0, stream>>>(Ob, Wob, bo, X, Yb);
  k_ln<<<M_, 256, 0, stream>>>(Yb, gamma, beta, (float*)d_out);
}

// Round 8
// 323.489 us; speedup vs baseline: 1.1813x; 1.1813x over previous
//
#include <hip/hip_runtime.h>
#include <hip/hip_bf16.h>

#define B_ 4
#define S_ 2048
#define D_ 1024
#define H_ 16
#define HD_ 64
#define M_ (B_*S_)
#define BH_ (B_*H_)

typedef __bf16 bf16;
typedef __attribute__((ext_vector_type(8))) __bf16 bf16x8;
typedef __attribute__((ext_vector_type(4))) __bf16 bf16x4;
typedef __attribute__((ext_vector_type(4))) float f32x4;
typedef __attribute__((ext_vector_type(16))) float f32x16;
typedef __attribute__((ext_vector_type(4))) unsigned u32x4;

#define MFMA16(a,b,c) __builtin_amdgcn_mfma_f32_16x16x32_bf16((a),(b),(c),0,0,0)
#define MFMA32(a,b,c) __builtin_amdgcn_mfma_f32_32x32x16_bf16((a),(b),(c),0,0,0)

__device__ __forceinline__ void gl2lds16(const void* g, void* l) {
  __builtin_amdgcn_global_load_lds(
      (__attribute__((address_space(1))) void*)(g),
      (__attribute__((address_space(3))) void*)(l), 16, 0, 0);
}

__device__ __forceinline__ float fexp2(float x) {
  float r;
  asm("v_exp_f32 %0, %1" : "=v"(r) : "v"(x));
  return r;
}

__device__ __forceinline__ unsigned cvtpk(float lo, float hi) {
  unsigned r;
  asm("v_cvt_pk_bf16_f32 %0, %1, %2" : "=v"(r) : "v"(lo), "v"(hi));
  return r;
}

// Fragment-tiled layout for GEMM operands (128-row x 64-k tiles):
//   T[(m,k)] = ((yt*16 + kt)*16 + f)*512 + lane*8 + e
//   yt=m>>7, kt=k>>6, f=((m>>4)&7)*2 + ((k>>5)&1),
//   lane=((k>>3)&3)*16 + (m&15), e=k&7.
// -> a wave's global_load_lds of one frag is 1KB contiguous, LDS is
//    frag-linear (ds_read_b128 at lane*16 = conflict-free, PMC-verified R6).

// ---------------- f32 -> tiled bf16 convert ----------------
__global__ __launch_bounds__(256) void k_cvt_t(const float* __restrict__ in,
                                               bf16* __restrict__ out, int nrow) {
  const int u = blockIdx.x * 256 + threadIdx.x;
  if (u >= nrow * 128) return;
  const int m = u >> 7, kc = u & 127;  // k = kc*8
  f32x4 v0 = *(const f32x4*)(in + (size_t)m * D_ + kc * 8);
  f32x4 v1 = *(const f32x4*)(in + (size_t)m * D_ + kc * 8 + 4);
  bf16x8 o;
  o[0]=(bf16)v0[0]; o[1]=(bf16)v0[1]; o[2]=(bf16)v0[2]; o[3]=(bf16)v0[3];
  o[4]=(bf16)v1[0]; o[5]=(bf16)v1[1]; o[6]=(bf16)v1[2]; o[7]=(bf16)v1[3];
  const int yt = m >> 7, kt = kc >> 3;
  const int f = ((m >> 4) & 7) * 2 + ((kc >> 2) & 1);
  const int lane = (kc & 3) * 16 + (m & 15);
  *(bf16x8*)&out[((size_t)(yt * 16 + kt) * 16 + f) * 512 + lane * 8] = o;
}

// ============ fused QKV GEMM (tiled in, Q row-major / K,V frag-tiled out) =====
__global__ __launch_bounds__(512, 4) void k_gemm_qkv(
    const bf16* __restrict__ At, const bf16* __restrict__ Wt,
    const float* __restrict__ bq, const float* __restrict__ bk,
    const float* __restrict__ bvp,
    bf16* __restrict__ Qb, bf16* __restrict__ Kb, bf16* __restrict__ Vt,
    float scl_q) {
  __shared__ __align__(16) bf16 As[2][16 * 512];
  __shared__ __align__(16) bf16 Bs[2][16 * 512];
  const int t = threadIdx.x;
  const int l = t & 63, w = t >> 6;
  const int g = l >> 4, c = l & 15;
  const int wm = w >> 2, wn = w & 3;

  const int bid = blockIdx.x;
  const int lg = (bid & 7) * 192 + (bid >> 3);   // bijective XCD swizzle
  const int xt = lg % 24, yt = lg / 24;
  const int m0 = yt * 128;

  const bf16* Ab = At + (size_t)yt * 8192 * 16;
  const bf16* Bb = Wt + (size_t)xt * 8192 * 16;

  f32x4 acc[4][2];
#pragma unroll
  for (int i = 0; i < 4; ++i)
#pragma unroll
    for (int j = 0; j < 2; ++j) acc[i][j] = (f32x4)(0.0f);

#define STG(buf, kt)                                                          \
  do {                                                                        \
    for (int p = 0; p < 2; ++p) {                                             \
      const int f = p * 8 + w;                                                \
      gl2lds16(Ab + (size_t)(kt) * 8192 + f * 512 + l * 8, &As[buf][f * 512]);\
      gl2lds16(Bb + (size_t)(kt) * 8192 + f * 512 + l * 8, &Bs[buf][f * 512]);\
    }                                                                         \
  } while (0)

  STG(0, 0);
  __syncthreads();

  for (int kt = 0; kt < D_ / 64; ++kt) {
    const int cur = kt & 1;
    if (kt + 1 < D_ / 64) STG(cur ^ 1, kt + 1);
#pragma unroll
    for (int kk = 0; kk < 2; ++kk) {
      bf16x8 af[4], bw[2];
#pragma unroll
      for (int i = 0; i < 4; ++i)
        af[i] = *(const bf16x8*)&As[cur][(((wm * 4 + i) * 2 + kk) * 512) + l * 8];
#pragma unroll
      for (int j = 0; j < 2; ++j)
        bw[j] = *(const bf16x8*)&Bs[cur][(((wn * 2 + j) * 2 + kk) * 512) + l * 8];
#pragma unroll
      for (int i = 0; i < 4; ++i)
#pragma unroll
        for (int j = 0; j < 2; ++j) acc[i][j] = MFMA16(af[i], bw[j], acc[i][j]);
    }
    __syncthreads();
  }
#undef STG

  const int sec = xt >> 3;                       // 0=Q, 1=K, 2=V
  const int nbase = (xt & 7) * 128 + wn * 32;
  const float* bptr = (sec == 0) ? bq : (sec == 1) ? bk : bvp;
  const float scl = (sec == 0) ? scl_q : 1.0f;

  float bvj[2];
#pragma unroll
  for (int j = 0; j < 2; ++j) bvj[j] = bptr[nbase + j * 16 + c];

#pragma unroll
  for (int i = 0; i < 4; ++i) {
#pragma unroll
    for (int j = 0; j < 2; ++j) {
#pragma unroll
      for (int r = 0; r < 4; ++r) {
        const int m = m0 + wm * 64 + i * 16 + g * 4 + r;
        const int n = nbase + j * 16 + c;
        const float v = (acc[i][j][r] + bvj[j]) * scl;
        const int b = m >> 11, s = m & (S_ - 1);
        const int h = n >> 6, hd = n & 63;
        const size_t hb = ((size_t)(b * H_ + h)) * S_ * HD_;
        if (sec == 0) {
          Qb[hb + (size_t)s * HD_ + hd] = (bf16)v;
        } else if (sec == 1) {
          const int f = (hd >> 4) * 2 + ((s >> 5) & 1);
          const int lane = (s & 31) + ((hd >> 3) & 1) * 32;
          Kb[hb + (s >> 6) * 4096 + f * 512 + lane * 8 + (hd & 7)] = (bf16)v;
        } else {
          const int sl = s & 63;
          const int f = (sl >> 4) * 2 + (hd >> 5);
          const int lane = (hd & 31) + ((sl >> 3) & 1) * 32;
          Vt[hb + (s >> 6) * 4096 + f * 512 + lane * 8 + (sl & 7)] = (bf16)v;
        }
      }
    }
  }
}

// ============ O-projection GEMM + residual (tiled A/W in, f32 out) ============
__global__ __launch_bounds__(512, 4) void k_gemm_o(
    const bf16* __restrict__ At, const bf16* __restrict__ Wt,
    const float* __restrict__ bias, const float* __restrict__ Xres,
    float* __restrict__ Yb) {
  __shared__ __align__(16) bf16 As[2][16 * 512];
  __shared__ __align__(16) bf16 Bs[2][16 * 512];
  const int t = threadIdx.x;
  const int l = t & 63, w = t >> 6;
  const int g = l >> 4, c = l & 15;
  const int wm = w >> 2, wn = w & 3;

  const int bid = blockIdx.x;
  const int lg = (bid & 7) * 64 + (bid >> 3);
  const int xt = lg & 7, yt = lg >> 3;
  const int m0 = yt * 128, n0 = xt * 128;

  const bf16* Ab = At + (size_t)yt * 8192 * 16;
  const bf16* Bb = Wt + (size_t)xt * 8192 * 16;

  f32x4 acc[4][2];
#pragma unroll
  for (int i = 0; i < 4; ++i)
#pragma unroll
    for (int j = 0; j < 2; ++j) acc[i][j] = (f32x4)(0.0f);

#define STG(buf, kt)                                                          \
  do {                                                                        \
    for (int p = 0; p < 2; ++p) {                                             \
      const int f = p * 8 + w;                                                \
      gl2lds16(Ab + (size_t)(kt) * 8192 + f * 512 + l * 8, &As[buf][f * 512]);\
      gl2lds16(Bb + (size_t)(kt) * 8192 + f * 512 + l * 8, &Bs[buf][f * 512]);\
    }                                                                         \
  } while (0)

  STG(0, 0);
  __syncthreads();

  for (int kt = 0; kt < D_ / 64; ++kt) {
    const int cur = kt & 1;
    if (kt + 1 < D_ / 64) STG(cur ^ 1, kt + 1);
#pragma unroll
    for (int kk = 0; kk < 2; ++kk) {
      bf16x8 af[4], bw[2];
#pragma unroll
      for (int i = 0; i < 4; ++i)
        af[i] = *(const bf16x8*)&As[cur][(((wm * 4 + i) * 2 + kk) * 512) + l * 8];
#pragma unroll
      for (int j = 0; j < 2; ++j)
        bw[j] = *(const bf16x8*)&Bs[cur][(((wn * 2 + j) * 2 + kk) * 512) + l * 8];
#pragma unroll
      for (int i = 0; i < 4; ++i)
#pragma unroll
        for (int j = 0; j < 2; ++j) acc[i][j] = MFMA16(af[i], bw[j], acc[i][j]);
    }
    __syncthreads();
  }
#undef STG

  float bvj[2];
#pragma unroll
  for (int j = 0; j < 2; ++j) bvj[j] = bias[n0 + wn * 32 + j * 16 + c];

#pragma unroll
  for (int i = 0; i < 4; ++i) {
#pragma unroll
    for (int j = 0; j < 2; ++j) {
#pragma unroll
      for (int r = 0; r < 4; ++r) {
        const int m = m0 + wm * 64 + i * 16 + g * 4 + r;
        const int n = n0 + wn * 32 + j * 16 + c;
        Yb[(size_t)m * D_ + n] =
            acc[i][j][r] + bvj[j] + Xres[(size_t)m * D_ + n];
      }
    }
  }
}

// ---------------- flash attention (tiled K/V staging, tiled O out) -----------
__global__ __launch_bounds__(256, 4) void k_attn(const bf16* __restrict__ Q,
                                                 const bf16* __restrict__ Kb,
                                                 const bf16* __restrict__ Vt,
                                                 bf16* __restrict__ Obt) {
  __shared__ __align__(16) bf16 Ks[2][8 * 512];
  __shared__ __align__(16) bf16 Vs[2][8 * 512];
  const int t = threadIdx.x;
  const int l = t & 63, w = t >> 6;
  const int c32 = l & 31, hi = l >> 5;

  const int bid = blockIdx.x;
  const int lg = (bid & 7) * 128 + (bid >> 3);
  const int bh = lg >> 4;
  const int q0 = (lg & 15) * 128 + w * 32;

  const bf16* Qh = Q + (size_t)bh * S_ * HD_;
  const bf16* Kt = Kb + (size_t)bh * S_ * HD_;
  const bf16* Vb = Vt + (size_t)bh * S_ * HD_;

  bf16x8 qf[4];
#pragma unroll
  for (int kk = 0; kk < 4; ++kk)
    qf[kk] = *(const bf16x8*)&Qh[(size_t)(q0 + c32) * HD_ + kk * 16 + hi * 8];

  f32x16 acc0 = (f32x16)(0.f), acc1 = (f32x16)(0.f);
  float m_c = -__builtin_inff(), l_c = 0.f;

#define STGA(buf, kt)                                                         \
  do {                                                                        \
    for (int p = 0; p < 2; ++p) {                                             \
      const int f = p * 4 + w;                                                \
      gl2lds16(Kt + (size_t)(kt) * 4096 + f * 512 + l * 8, &Ks[buf][f * 512]);\
      gl2lds16(Vb + (size_t)(kt) * 4096 + f * 512 + l * 8, &Vs[buf][f * 512]);\
    }                                                                         \
  } while (0)

  STGA(0, 0);
  __syncthreads();

  for (int kt = 0; kt < S_ / 64; ++kt) {
    const int cur = kt & 1;
    if (kt + 1 < S_ / 64) STGA(cur ^ 1, kt + 1);

    // ---- QK^T (swapped): st = K * Q^T ----
    f32x16 st0 = (f32x16)(0.f), st1 = (f32x16)(0.f);
    __builtin_amdgcn_s_setprio(1);
#pragma unroll
    for (int kk = 0; kk < 4; ++kk) {
      bf16x8 kf0 = *(const bf16x8*)&Ks[cur][(kk * 2) * 512 + l * 8];
      bf16x8 kf1 = *(const bf16x8*)&Ks[cur][(kk * 2 + 1) * 512 + l * 8];
      st0 = MFMA32(kf0, qf[kk], st0);
      st1 = MFMA32(kf1, qf[kk], st1);
    }
    __builtin_amdgcn_s_setprio(0);

    // ---- online softmax, one scalar state per lane (q = c32) ----
    float tm;
    {
      f32x16 mx;
#pragma unroll
      for (int r = 0; r < 16; ++r) mx[r] = fmaxf(st0[r], st1[r]);
      float m8[8];
#pragma unroll
      for (int r = 0; r < 8; ++r) m8[r] = fmaxf(mx[r], mx[r + 8]);
      float m4[4];
#pragma unroll
      for (int r = 0; r < 4; ++r) m4[r] = fmaxf(m8[r], m8[r + 4]);
      tm = fmaxf(fmaxf(m4[0], m4[1]), fmaxf(m4[2], m4[3]));
      tm = fmaxf(tm, __shfl_xor(tm, 32));
    }
    if (!__all(tm <= m_c + 8.f)) {   // defer-max (T13)
      const float mn = fmaxf(m_c, tm);
      const float cf = fexp2(m_c - mn);
      m_c = mn;
      l_c *= cf;
#pragma unroll
      for (int r = 0; r < 16; ++r) { acc0[r] *= cf; acc1[r] *= cf; }
    }
    float rs = 0.f;
#pragma unroll
    for (int r = 0; r < 16; ++r) { st0[r] = fexp2(st0[r] - m_c); rs += st0[r]; }
#pragma unroll
    for (int r = 0; r < 16; ++r) { st1[r] = fexp2(st1[r] - m_c); rs += st1[r]; }
    rs += __shfl_xor(rs, 32);
    l_c += rs;

    // ---- P^T -> bf16 B-fragments in-register (cvt_pk + permlane32_swap) ----
    unsigned ca[8], cb[8];
#pragma unroll
    for (int i = 0; i < 8; ++i) {
      ca[i] = cvtpk(st0[2 * i], st0[2 * i + 1]);
      cb[i] = cvtpk(st1[2 * i], st1[2 * i + 1]);
    }
    asm volatile("v_permlane32_swap_b32 %0, %1" : "+v"(ca[0]), "+v"(ca[2]));
    asm volatile("v_permlane32_swap_b32 %0, %1" : "+v"(ca[1]), "+v"(ca[3]));
    asm volatile("v_permlane32_swap_b32 %0, %1" : "+v"(ca[4]), "+v"(ca[6]));
    asm volatile("v_permlane32_swap_b32 %0, %1" : "+v"(ca[5]), "+v"(ca[7]));
    asm volatile("v_permlane32_swap_b32 %0, %1" : "+v"(cb[0]), "+v"(cb[2]));
    asm volatile("v_permlane32_swap_b32 %0, %1" : "+v"(cb[1]), "+v"(cb[3]));
    asm volatile("v_permlane32_swap_b32 %0, %1" : "+v"(cb[4]), "+v"(cb[6]));
    asm volatile("v_permlane32_swap_b32 %0, %1" : "+v"(cb[5]), "+v"(cb[7]));
    bf16x8 pf[4];
    pf[0] = __builtin_bit_cast(bf16x8, (u32x4){ca[0], ca[1], ca[2], ca[3]});
    pf[1] = __builtin_bit_cast(bf16x8, (u32x4){ca[4], ca[5], ca[6], ca[7]});
    pf[2] = __builtin_bit_cast(bf16x8, (u32x4){cb[0], cb[1], cb[2], cb[3]});
    pf[3] = __builtin_bit_cast(bf16x8, (u32x4){cb[4], cb[5], cb[6], cb[7]});

    // ---- PV (swapped): acc(O^T) += V^T * P^T ----
    __builtin_amdgcn_s_setprio(1);
#pragma unroll
    for (int kb = 0; kb < 4; ++kb) {
      bf16x8 vf0 = *(const bf16x8*)&Vs[cur][(kb * 2) * 512 + l * 8];
      bf16x8 vf1 = *(const bf16x8*)&Vs[cur][(kb * 2 + 1) * 512 + l * 8];
      acc0 = MFMA32(vf0, pf[kb], acc0);
      acc1 = MFMA32(vf1, pf[kb], acc1);
    }
    __builtin_amdgcn_s_setprio(0);

    __syncthreads();
  }
#undef STGA

  // ---- epilogue: write O in fragment-tiled layout (k = h*64 + dv) ----
  const float li = 1.f / l_c;
  const int b = bh >> 4, h = bh & 15;
  const int m = b * S_ + q0 + c32;
  const int yt2 = m >> 7, rb = (m >> 4) & 7, c16 = m & 15;
  bf16* tb = Obt + ((size_t)(yt2 * 16 + h) * 16) * 512;
#pragma unroll
  for (int rq = 0; rq < 4; ++rq) {
    bf16x4 o0, o1;
#pragma unroll
    for (int j = 0; j < 4; ++j) {
      o0[j] = (bf16)(acc0[rq * 4 + j] * li);
      o1[j] = (bf16)(acc1[rq * 4 + j] * li);
    }
    const int lo = (rq * 16 + c16) * 8 + hi * 4;
    *(bf16x4*)&tb[(rb * 2 + 0) * 512 + lo] = o0;
    *(bf16x4*)&tb[(rb * 2 + 1) * 512 + lo] = o1;
  }
}

// ---------------- LayerNorm (one block per row) ----------------
__global__ __launch_bounds__(256) void k_ln(const float* __restrict__ Y,
                                            const float* __restrict__ gamma,
                                            const float* __restrict__ beta,
                                            float* __restrict__ out) {
  __shared__ float red[8];
  const int row = blockIdx.x, t = threadIdx.x;
  const float* y = Y + (size_t)row * D_;
  f32x4 v = *(const f32x4*)(y + t * 4);
  float s = v[0] + v[1] + v[2] + v[3];
  float s2 = v[0]*v[0] + v[1]*v[1] + v[2]*v[2] + v[3]*v[3];
#pragma unroll
  for (int mk = 1; mk <= 32; mk <<= 1) {
    s += __shfl_xor(s, mk);
    s2 += __shfl_xor(s2, mk);
  }
  if ((t & 63) == 0) { red[t >> 6] = s; red[4 + (t >> 6)] = s2; }
  __syncthreads();
  const float ts = red[0] + red[1] + red[2] + red[3];
  const float ts2 = red[4] + red[5] + red[6] + red[7];
  const float mu = ts * (1.0f / D_);
  const float inv = rsqrtf(ts2 * (1.0f / D_) - mu * mu + 1e-12f);
  f32x4 gm = *(const f32x4*)(gamma + t * 4);
  f32x4 bt = *(const f32x4*)(beta + t * 4);
  f32x4 o;
#pragma unroll
  for (int j = 0; j < 4; ++j) o[j] = gm[j] * (v[j] - mu) * inv + bt[j];
  *(f32x4*)(out + (size_t)row * D_ + t * 4) = o;
}

extern "C" void kernel_launch(void* const* d_in, const int* in_sizes, int n_in,
                              void* d_out, int out_size, void* d_ws, size_t ws_size,
                              hipStream_t stream) {
  const float* X     = (const float*)d_in[0];
  const float* Wq    = (const float*)d_in[1];
  const float* bq    = (const float*)d_in[2];
  const float* Wk    = (const float*)d_in[3];
  const float* bk    = (const float*)d_in[4];
  const float* Wv    = (const float*)d_in[5];
  const float* bv    = (const float*)d_in[6];
  const float* Wo    = (const float*)d_in[7];
  const float* bo    = (const float*)d_in[8];
  const float* gamma = (const float*)d_in[9];
  const float* beta  = (const float*)d_in[10];

  char* ws = (char*)d_ws;
  bf16* Xt  = (bf16*)(ws + 0);                 // 16 MB tiled X
  bf16* Wct = (bf16*)(ws + (16u << 20));       // 6 MB tiled Wq|Wk|Wv
  bf16* Wot = (bf16*)(ws + (22u << 20));       // 2 MB tiled Wo
  bf16* Qb  = (bf16*)(ws + (24u << 20));       // 16 MB [bh][s][d] (pre-scaled)
  bf16* Kb  = (bf16*)(ws + (40u << 20));       // 16 MB frag-tiled per bh
  bf16* Vt  = (bf16*)(ws + (56u << 20));       // 16 MB frag-tiled per bh
  bf16* Obt = (bf16*)(ws + (72u << 20));       // 16 MB frag-tiled O
  float* Yb = (float*)(ws + (88u << 20));      // 32 MB

  const float SCL = 0.125f * 1.44269504088896340736f;  // 1/sqrt(64) * log2(e)
  const size_t WSZ = (size_t)D_ * D_;

  k_cvt_t<<<M_ * 128 / 256, 256, 0, stream>>>(X, Xt, M_);
  k_cvt_t<<<D_ * 128 / 256, 256, 0, stream>>>(Wq, Wct, D_);
  k_cvt_t<<<D_ * 128 / 256, 256, 0, stream>>>(Wk, Wct + WSZ, D_);
  k_cvt_t<<<D_ * 128 / 256, 256, 0, stream>>>(Wv, Wct + 2 * WSZ, D_);
  k_cvt_t<<<D_ * 128 / 256, 256, 0, stream>>>(Wo, Wot, D_);

  k_gemm_qkv<<<1536, 512, 0, stream>>>(Xt, Wct, bq, bk, bv, Qb, Kb, Vt, SCL);
  k_attn<<<1024, 256, 0, stream>>>(Qb, Kb, Vt, Obt);
  k_gemm_o<<<512, 512, 0, stream>>>(Obt, Wot, bo, X, Yb);
  k_ln<<<M_, 256, 0, stream>>>(Yb, gamma, beta, (float*)d_out);
}

// Round 9
// 304.186 us; speedup vs baseline: 1.2563x; 1.0635x over previous
//
#include <hip/hip_runtime.h>
#include <hip/hip_bf16.h>

#define B_ 4
#define S_ 2048
#define D_ 1024
#define H_ 16
#define HD_ 64
#define M_ (B_*S_)
#define BH_ (B_*H_)

typedef __bf16 bf16;
typedef __attribute__((ext_vector_type(8))) __bf16 bf16x8;
typedef __attribute__((ext_vector_type(4))) __bf16 bf16x4;
typedef __attribute__((ext_vector_type(4))) float f32x4;
typedef __attribute__((ext_vector_type(16))) float f32x16;
typedef __attribute__((ext_vector_type(4))) unsigned u32x4;

#define MFMA16(a,b,c) __builtin_amdgcn_mfma_f32_16x16x32_bf16((a),(b),(c),0,0,0)
#define MFMA32(a,b,c) __builtin_amdgcn_mfma_f32_32x32x16_bf16((a),(b),(c),0,0,0)

__device__ __forceinline__ void gl2lds16(const void* g, void* l) {
  __builtin_amdgcn_global_load_lds(
      (__attribute__((address_space(1))) void*)(g),
      (__attribute__((address_space(3))) void*)(l), 16, 0, 0);
}

__device__ __forceinline__ float fexp2(float x) {
  float r;
  asm("v_exp_f32 %0, %1" : "=v"(r) : "v"(x));
  return r;
}

__device__ __forceinline__ unsigned cvtpk(float lo, float hi) {
  unsigned r;
  asm("v_cvt_pk_bf16_f32 %0, %1, %2" : "=v"(r) : "v"(lo), "v"(hi));
  return r;
}

// Fragment-tiled layout for GEMM operands (128-row x 64-k tiles):
//   T[(m,k)] = ((yt*16 + kt)*16 + f)*512 + lane*8 + e
//   f=((m>>4)&7)*2 + ((k>>5)&1), lane=((k>>3)&3)*16 + (m&15), e=k&7.
// -> wave's global_load_lds of one frag = 1KB contiguous; LDS frag-linear
//    (ds_read_b128 at lane*16 = conflict-free; PMC-verified R6/R8).

// ---------------- f32 -> tiled bf16 convert ----------------
__global__ __launch_bounds__(256) void k_cvt_t(const float* __restrict__ in,
                                               bf16* __restrict__ out, int nrow) {
  const int u = blockIdx.x * 256 + threadIdx.x;
  if (u >= nrow * 128) return;
  const int m = u >> 7, kc = u & 127;  // k = kc*8
  f32x4 v0 = *(const f32x4*)(in + (size_t)m * D_ + kc * 8);
  f32x4 v1 = *(const f32x4*)(in + (size_t)m * D_ + kc * 8 + 4);
  bf16x8 o;
  o[0]=(bf16)v0[0]; o[1]=(bf16)v0[1]; o[2]=(bf16)v0[2]; o[3]=(bf16)v0[3];
  o[4]=(bf16)v1[0]; o[5]=(bf16)v1[1]; o[6]=(bf16)v1[2]; o[7]=(bf16)v1[3];
  const int yt = m >> 7, kt = kc >> 3;
  const int f = ((m >> 4) & 7) * 2 + ((kc >> 2) & 1);
  const int lane = (kc & 3) * 16 + (m & 15);
  *(bf16x8*)&out[((size_t)(yt * 16 + kt) * 16 + f) * 512 + lane * 8] = o;
}

// ============ fused QKV GEMM — m97-style single-buffer, 4 blocks/CU ==========
__global__ __launch_bounds__(512, 4) void k_gemm_qkv(
    const bf16* __restrict__ At, const bf16* __restrict__ Wt,
    const float* __restrict__ bq, const float* __restrict__ bk,
    const float* __restrict__ bvp,
    bf16* __restrict__ Qb, bf16* __restrict__ Kb, bf16* __restrict__ Vt,
    float scl_q) {
  __shared__ __align__(16) bf16 As[16 * 512];
  __shared__ __align__(16) bf16 Bs[16 * 512];
  const int t = threadIdx.x;
  const int l = t & 63, w = t >> 6;
  const int g = l >> 4, c = l & 15;
  const int wm = w >> 2, wn = w & 3;

  const int bid = blockIdx.x;
  const int lg = (bid & 7) * 192 + (bid >> 3);   // bijective XCD swizzle
  const int xt = lg % 24, yt = lg / 24;
  const int m0 = yt * 128;

  const bf16* Ab = At + (size_t)yt * 8192 * 16;
  const bf16* Bb = Wt + (size_t)xt * 8192 * 16;

  f32x4 acc[4][2];
#pragma unroll
  for (int i = 0; i < 4; ++i)
#pragma unroll
    for (int j = 0; j < 2; ++j) acc[i][j] = (f32x4)(0.0f);

  for (int kt = 0; kt < D_ / 64; ++kt) {
#pragma unroll
    for (int p = 0; p < 2; ++p) {
      const int f = p * 8 + w;
      gl2lds16(Ab + (size_t)kt * 8192 + f * 512 + l * 8, &As[f * 512]);
      gl2lds16(Bb + (size_t)kt * 8192 + f * 512 + l * 8, &Bs[f * 512]);
    }
    __syncthreads();
#pragma unroll
    for (int kk = 0; kk < 2; ++kk) {
      bf16x8 af[4], bw[2];
#pragma unroll
      for (int i = 0; i < 4; ++i)
        af[i] = *(const bf16x8*)&As[(((wm * 4 + i) * 2 + kk) * 512) + l * 8];
#pragma unroll
      for (int j = 0; j < 2; ++j)
        bw[j] = *(const bf16x8*)&Bs[(((wn * 2 + j) * 2 + kk) * 512) + l * 8];
#pragma unroll
      for (int i = 0; i < 4; ++i)
#pragma unroll
        for (int j = 0; j < 2; ++j) acc[i][j] = MFMA16(af[i], bw[j], acc[i][j]);
    }
    __syncthreads();
  }

  const int sec = xt >> 3;                       // 0=Q, 1=K, 2=V
  const int nbase = (xt & 7) * 128 + wn * 32;
  const float* bptr = (sec == 0) ? bq : (sec == 1) ? bk : bvp;
  const float scl = (sec == 0) ? scl_q : 1.0f;

  float bvj[2];
#pragma unroll
  for (int j = 0; j < 2; ++j) bvj[j] = bptr[nbase + j * 16 + c];

#pragma unroll
  for (int i = 0; i < 4; ++i) {
#pragma unroll
    for (int j = 0; j < 2; ++j) {
#pragma unroll
      for (int r = 0; r < 4; ++r) {
        const int m = m0 + wm * 64 + i * 16 + g * 4 + r;
        const int n = nbase + j * 16 + c;
        const float v = (acc[i][j][r] + bvj[j]) * scl;
        const int b = m >> 11, s = m & (S_ - 1);
        const int h = n >> 6, hd = n & 63;
        const size_t hb = ((size_t)(b * H_ + h)) * S_ * HD_;
        if (sec == 0) {
          Qb[hb + (size_t)s * HD_ + hd] = (bf16)v;
        } else if (sec == 1) {
          const int f = (hd >> 4) * 2 + ((s >> 5) & 1);
          const int lane = (s & 31) + ((hd >> 3) & 1) * 32;
          Kb[hb + (s >> 6) * 4096 + f * 512 + lane * 8 + (hd & 7)] = (bf16)v;
        } else {
          const int sl = s & 63;
          const int f = (sl >> 4) * 2 + (hd >> 5);
          const int lane = (hd & 31) + ((sl >> 3) & 1) * 32;
          Vt[hb + (s >> 6) * 4096 + f * 512 + lane * 8 + (sl & 7)] = (bf16)v;
        }
      }
    }
  }
}

// ============ O-projection GEMM + residual — single-buffer ====================
__global__ __launch_bounds__(512, 4) void k_gemm_o(
    const bf16* __restrict__ At, const bf16* __restrict__ Wt,
    const float* __restrict__ bias, const float* __restrict__ Xres,
    float* __restrict__ Yb) {
  __shared__ __align__(16) bf16 As[16 * 512];
  __shared__ __align__(16) bf16 Bs[16 * 512];
  const int t = threadIdx.x;
  const int l = t & 63, w = t >> 6;
  const int g = l >> 4, c = l & 15;
  const int wm = w >> 2, wn = w & 3;

  const int bid = blockIdx.x;
  const int lg = (bid & 7) * 64 + (bid >> 3);
  const int xt = lg & 7, yt = lg >> 3;
  const int m0 = yt * 128, n0 = xt * 128;

  const bf16* Ab = At + (size_t)yt * 8192 * 16;
  const bf16* Bb = Wt + (size_t)xt * 8192 * 16;

  f32x4 acc[4][2];
#pragma unroll
  for (int i = 0; i < 4; ++i)
#pragma unroll
    for (int j = 0; j < 2; ++j) acc[i][j] = (f32x4)(0.0f);

  for (int kt = 0; kt < D_ / 64; ++kt) {
#pragma unroll
    for (int p = 0; p < 2; ++p) {
      const int f = p * 8 + w;
      gl2lds16(Ab + (size_t)kt * 8192 + f * 512 + l * 8, &As[f * 512]);
      gl2lds16(Bb + (size_t)kt * 8192 + f * 512 + l * 8, &Bs[f * 512]);
    }
    __syncthreads();
#pragma unroll
    for (int kk = 0; kk < 2; ++kk) {
      bf16x8 af[4], bw[2];
#pragma unroll
      for (int i = 0; i < 4; ++i)
        af[i] = *(const bf16x8*)&As[(((wm * 4 + i) * 2 + kk) * 512) + l * 8];
#pragma unroll
      for (int j = 0; j < 2; ++j)
        bw[j] = *(const bf16x8*)&Bs[(((wn * 2 + j) * 2 + kk) * 512) + l * 8];
#pragma unroll
      for (int i = 0; i < 4; ++i)
#pragma unroll
        for (int j = 0; j < 2; ++j) acc[i][j] = MFMA16(af[i], bw[j], acc[i][j]);
    }
    __syncthreads();
  }

  float bvj[2];
#pragma unroll
  for (int j = 0; j < 2; ++j) bvj[j] = bias[n0 + wn * 32 + j * 16 + c];

#pragma unroll
  for (int i = 0; i < 4; ++i) {
#pragma unroll
    for (int j = 0; j < 2; ++j) {
#pragma unroll
      for (int r = 0; r < 4; ++r) {
        const int m = m0 + wm * 64 + i * 16 + g * 4 + r;
        const int n = n0 + wn * 32 + j * 16 + c;
        Yb[(size_t)m * D_ + n] =
            acc[i][j][r] + bvj[j] + Xres[(size_t)m * D_ + n];
      }
    }
  }
}

// ---------------- flash attention (tiled K/V, MFMA row-sum, max3 tree) -------
__global__ __launch_bounds__(256, 4) void k_attn(const bf16* __restrict__ Q,
                                                 const bf16* __restrict__ Kb,
                                                 const bf16* __restrict__ Vt,
                                                 bf16* __restrict__ Obt) {
  __shared__ __align__(16) bf16 Ks[2][8 * 512];
  __shared__ __align__(16) bf16 Vs[2][8 * 512];
  const int t = threadIdx.x;
  const int l = t & 63, w = t >> 6;
  const int c32 = l & 31, hi = l >> 5;

  const int bid = blockIdx.x;
  const int lg = (bid & 7) * 128 + (bid >> 3);
  const int bh = lg >> 4;
  const int q0 = (lg & 15) * 128 + w * 32;

  const bf16* Qh = Q + (size_t)bh * S_ * HD_;
  const bf16* Kt = Kb + (size_t)bh * S_ * HD_;
  const bf16* Vb = Vt + (size_t)bh * S_ * HD_;

  bf16x8 qf[4];
#pragma unroll
  for (int kk = 0; kk < 4; ++kk)
    qf[kk] = *(const bf16x8*)&Qh[(size_t)(q0 + c32) * HD_ + kk * 16 + hi * 8];

  bf16x8 onesf;
#pragma unroll
  for (int i = 0; i < 8; ++i) onesf[i] = (bf16)1.0f;

  f32x16 acc0 = (f32x16)(0.f), acc1 = (f32x16)(0.f), accl = (f32x16)(0.f);
  float m_c = -__builtin_inff();

#define STGA(buf, kt)                                                         \
  do {                                                                        \
    for (int p = 0; p < 2; ++p) {                                             \
      const int f = p * 4 + w;                                                \
      gl2lds16(Kt + (size_t)(kt) * 4096 + f * 512 + l * 8, &Ks[buf][f * 512]);\
      gl2lds16(Vb + (size_t)(kt) * 4096 + f * 512 + l * 8, &Vs[buf][f * 512]);\
    }                                                                         \
  } while (0)

  STGA(0, 0);
  __syncthreads();

  for (int kt = 0; kt < S_ / 64; ++kt) {
    const int cur = kt & 1;
    if (kt + 1 < S_ / 64) STGA(cur ^ 1, kt + 1);

    // ---- QK^T (swapped): st = K * Q^T ----
    f32x16 st0 = (f32x16)(0.f), st1 = (f32x16)(0.f);
    __builtin_amdgcn_s_setprio(1);
#pragma unroll
    for (int kk = 0; kk < 4; ++kk) {
      bf16x8 kf0 = *(const bf16x8*)&Ks[cur][(kk * 2) * 512 + l * 8];
      bf16x8 kf1 = *(const bf16x8*)&Ks[cur][(kk * 2 + 1) * 512 + l * 8];
      st0 = MFMA32(kf0, qf[kk], st0);
      st1 = MFMA32(kf1, qf[kk], st1);
    }
    __builtin_amdgcn_s_setprio(0);

    // ---- tile max via max3-fusable triples (32 vals -> 1) ----
    float tm;
    {
      float a0 = fmaxf(fmaxf(st0[0], st0[1]), st0[2]);
      float a1 = fmaxf(fmaxf(st0[3], st0[4]), st0[5]);
      float a2 = fmaxf(fmaxf(st0[6], st0[7]), st0[8]);
      float a3 = fmaxf(fmaxf(st0[9], st0[10]), st0[11]);
      float a4 = fmaxf(fmaxf(st0[12], st0[13]), st0[14]);
      float a5 = fmaxf(fmaxf(st0[15], st1[0]), st1[1]);
      float a6 = fmaxf(fmaxf(st1[2], st1[3]), st1[4]);
      float a7 = fmaxf(fmaxf(st1[5], st1[6]), st1[7]);
      float a8 = fmaxf(fmaxf(st1[8], st1[9]), st1[10]);
      float a9 = fmaxf(fmaxf(st1[11], st1[12]), st1[13]);
      float a10 = fmaxf(st1[14], st1[15]);
      float b0 = fmaxf(fmaxf(a0, a1), a2);
      float b1 = fmaxf(fmaxf(a3, a4), a5);
      float b2 = fmaxf(fmaxf(a6, a7), a8);
      float b3 = fmaxf(a9, a10);
      float cx = fmaxf(fmaxf(b0, b1), fmaxf(b2, b3));
      tm = fmaxf(cx, __shfl_xor(cx, 32));
    }
    if (!__all(tm <= m_c + 8.f)) {   // defer-max (T13)
      const float mn = fmaxf(m_c, tm);
      const float cf = fexp2(m_c - mn);
      m_c = mn;
      accl[0] *= cf;
#pragma unroll
      for (int r = 0; r < 16; ++r) { acc0[r] *= cf; acc1[r] *= cf; }
    }
#pragma unroll
    for (int r = 0; r < 16; ++r) st0[r] = fexp2(st0[r] - m_c);
#pragma unroll
    for (int r = 0; r < 16; ++r) st1[r] = fexp2(st1[r] - m_c);

    // ---- P^T -> bf16 B-fragments in-register (cvt_pk + permlane32_swap) ----
    unsigned ca[8], cb[8];
#pragma unroll
    for (int i = 0; i < 8; ++i) {
      ca[i] = cvtpk(st0[2 * i], st0[2 * i + 1]);
      cb[i] = cvtpk(st1[2 * i], st1[2 * i + 1]);
    }
    asm volatile("v_permlane32_swap_b32 %0, %1" : "+v"(ca[0]), "+v"(ca[2]));
    asm volatile("v_permlane32_swap_b32 %0, %1" : "+v"(ca[1]), "+v"(ca[3]));
    asm volatile("v_permlane32_swap_b32 %0, %1" : "+v"(ca[4]), "+v"(ca[6]));
    asm volatile("v_permlane32_swap_b32 %0, %1" : "+v"(ca[5]), "+v"(ca[7]));
    asm volatile("v_permlane32_swap_b32 %0, %1" : "+v"(cb[0]), "+v"(cb[2]));
    asm volatile("v_permlane32_swap_b32 %0, %1" : "+v"(cb[1]), "+v"(cb[3]));
    asm volatile("v_permlane32_swap_b32 %0, %1" : "+v"(cb[4]), "+v"(cb[6]));
    asm volatile("v_permlane32_swap_b32 %0, %1" : "+v"(cb[5]), "+v"(cb[7]));
    bf16x8 pf[4];
    pf[0] = __builtin_bit_cast(bf16x8, (u32x4){ca[0], ca[1], ca[2], ca[3]});
    pf[1] = __builtin_bit_cast(bf16x8, (u32x4){ca[4], ca[5], ca[6], ca[7]});
    pf[2] = __builtin_bit_cast(bf16x8, (u32x4){cb[0], cb[1], cb[2], cb[3]});
    pf[3] = __builtin_bit_cast(bf16x8, (u32x4){cb[4], cb[5], cb[6], cb[7]});

    // ---- PV (swapped): acc(O^T) += V^T * P^T; accl += 1^T * P^T (row sums) --
    __builtin_amdgcn_s_setprio(1);
#pragma unroll
    for (int kb = 0; kb < 4; ++kb) {
      bf16x8 vf0 = *(const bf16x8*)&Vs[cur][(kb * 2) * 512 + l * 8];
      bf16x8 vf1 = *(const bf16x8*)&Vs[cur][(kb * 2 + 1) * 512 + l * 8];
      acc0 = MFMA32(vf0, pf[kb], acc0);
      acc1 = MFMA32(vf1, pf[kb], acc1);
      accl = MFMA32(onesf, pf[kb], accl);
    }
    __builtin_amdgcn_s_setprio(0);

    __syncthreads();
  }
#undef STGA

  // ---- epilogue: write O in fragment-tiled layout (k = h*64 + dv) ----
  const float li = 1.f / accl[0];
  const int b = bh >> 4, h = bh & 15;
  const int m = b * S_ + q0 + c32;
  const int yt2 = m >> 7, rb = (m >> 4) & 7, c16 = m & 15;
  bf16* tb = Obt + ((size_t)(yt2 * 16 + h) * 16) * 512;
#pragma unroll
  for (int rq = 0; rq < 4; ++rq) {
    bf16x4 o0, o1;
#pragma unroll
    for (int j = 0; j < 4; ++j) {
      o0[j] = (bf16)(acc0[rq * 4 + j] * li);
      o1[j] = (bf16)(acc1[rq * 4 + j] * li);
    }
    const int lo = (rq * 16 + c16) * 8 + hi * 4;
    *(bf16x4*)&tb[(rb * 2 + 0) * 512 + lo] = o0;
    *(bf16x4*)&tb[(rb * 2 + 1) * 512 + lo] = o1;
  }
}

// ---------------- LayerNorm (one block per row) ----------------
__global__ __launch_bounds__(256) void k_ln(const float* __restrict__ Y,
                                            const float* __restrict__ gamma,
                                            const float* __restrict__ beta,
                                            float* __restrict__ out) {
  __shared__ float red[8];
  const int row = blockIdx.x, t = threadIdx.x;
  const float* y = Y + (size_t)row * D_;
  f32x4 v = *(const f32x4*)(y + t * 4);
  float s = v[0] + v[1] + v[2] + v[3];
  float s2 = v[0]*v[0] + v[1]*v[1] + v[2]*v[2] + v[3]*v[3];
#pragma unroll
  for (int mk = 1; mk <= 32; mk <<= 1) {
    s += __shfl_xor(s, mk);
    s2 += __shfl_xor(s2, mk);
  }
  if ((t & 63) == 0) { red[t >> 6] = s; red[4 + (t >> 6)] = s2; }
  __syncthreads();
  const float ts = red[0] + red[1] + red[2] + red[3];
  const float ts2 = red[4] + red[5] + red[6] + red[7];
  const float mu = ts * (1.0f / D_);
  const float inv = rsqrtf(ts2 * (1.0f / D_) - mu * mu + 1e-12f);
  f32x4 gm = *(const f32x4*)(gamma + t * 4);
  f32x4 bt = *(const f32x4*)(beta + t * 4);
  f32x4 o;
#pragma unroll
  for (int j = 0; j < 4; ++j) o[j] = gm[j] * (v[j] - mu) * inv + bt[j];
  *(f32x4*)(out + (size_t)row * D_ + t * 4) = o;
}

extern "C" void kernel_launch(void* const* d_in, const int* in_sizes, int n_in,
                              void* d_out, int out_size, void* d_ws, size_t ws_size,
                              hipStream_t stream) {
  const float* X     = (const float*)d_in[0];
  const float* Wq    = (const float*)d_in[1];
  const float* bq    = (const float*)d_in[2];
  const float* Wk    = (const float*)d_in[3];
  const float* bk    = (const float*)d_in[4];
  const float* Wv    = (const float*)d_in[5];
  const float* bv    = (const float*)d_in[6];
  const float* Wo    = (const float*)d_in[7];
  const float* bo    = (const float*)d_in[8];
  const float* gamma = (const float*)d_in[9];
  const float* beta  = (const float*)d_in[10];

  char* ws = (char*)d_ws;
  bf16* Xt  = (bf16*)(ws + 0);                 // 16 MB tiled X
  bf16* Wct = (bf16*)(ws + (16u << 20));       // 6 MB tiled Wq|Wk|Wv
  bf16* Wot = (bf16*)(ws + (22u << 20));       // 2 MB tiled Wo
  bf16* Qb  = (bf16*)(ws + (24u << 20));       // 16 MB [bh][s][d] (pre-scaled)
  bf16* Kb  = (bf16*)(ws + (40u << 20));       // 16 MB frag-tiled per bh
  bf16* Vt  = (bf16*)(ws + (56u << 20));       // 16 MB frag-tiled per bh
  bf16* Obt = (bf16*)(ws + (72u << 20));       // 16 MB frag-tiled O
  float* Yb = (float*)(ws + (88u << 20));      // 32 MB

  const float SCL = 0.125f * 1.44269504088896340736f;  // 1/sqrt(64) * log2(e)
  const size_t WSZ = (size_t)D_ * D_;

  k_cvt_t<<<M_ * 128 / 256, 256, 0, stream>>>(X, Xt, M_);
  k_cvt_t<<<D_ * 128 / 256, 256, 0, stream>>>(Wq, Wct, D_);
  k_cvt_t<<<D_ * 128 / 256, 256, 0, stream>>>(Wk, Wct + WSZ, D_);
  k_cvt_t<<<D_ * 128 / 256, 256, 0, stream>>>(Wv, Wct + 2 * WSZ, D_);
  k_cvt_t<<<D_ * 128 / 256, 256, 0, stream>>>(Wo, Wot, D_);

  k_gemm_qkv<<<1536, 512, 0, stream>>>(Xt, Wct, bq, bk, bv, Qb, Kb, Vt, SCL);
  k_attn<<<1024, 256, 0, stream>>>(Qb, Kb, Vt, Obt);
  k_gemm_o<<<512, 512, 0, stream>>>(Obt, Wot, bo, X, Yb);
  k_ln<<<M_, 256, 0, stream>>>(Yb, gamma, beta, (float*)d_out);
}